// Round 4
// baseline (105.526 us; speedup 1.0000x reference)
//
#include <hip/hip_runtime.h>
#include <math.h>

// Problem constants (match reference)
#define BB 4
#define SS 2048
#define EE 16
#define HH 4
#define DK 4
#define KS 32                 // key splits: 512 blocks = 2 waves/SIMD
#define NQ (BB*HH*SS)         // 32768 total query rows
#define KLEN (SS/KS)          // 64 keys per split
#define QPT 8                 // queries per thread

// q pre-scaled by (1/sqrt(DK)) * log2(e): attn loop is pure exp2 domain.
// No-running-max softmax is safe: |log2-score| <= ~16 worst case, exp2 sums
// stay far below fp32 overflow; matches reference softmax exactly in exact math.
#define QSCALE 0.7213475204444817f   // 0.5 * log2(e)

typedef float v2f __attribute__((ext_vector_type(2)));

// ---------------------------------------------------------------------------
// Kernel A: per-token projection. q = cos(x+theta)*QSCALE ; k = x@Wk^T ;
// v = x@Wv^T. Stored per-head-contiguous: qarr[(bh*S+s)*4], kv[(bh*S+s)*8]
// = {k0..k3, v0..v3}.
// ---------------------------------------------------------------------------
__global__ __launch_bounds__(256) void proj_kernel(
    const float* __restrict__ x, const float* __restrict__ theta,
    const float* __restrict__ Wk, const float* __restrict__ Wv,
    float* __restrict__ qarr, float* __restrict__ kv)
{
    int t = blockIdx.x * 256 + threadIdx.x;   // token 0..8191
    int b = t >> 11;
    int s = t & (SS - 1);

    float xv[EE];
    const float4* xr = reinterpret_cast<const float4*>(x + t * EE);
    #pragma unroll
    for (int e4 = 0; e4 < 4; ++e4) {
        float4 v = xr[e4];
        xv[e4*4+0] = v.x; xv[e4*4+1] = v.y; xv[e4*4+2] = v.z; xv[e4*4+3] = v.w;
    }

    float qv[EE];
    #pragma unroll
    for (int e = 0; e < EE; ++e)
        qv[e] = __cosf(xv[e] + theta[e]) * QSCALE;

    float kd[EE], vd[EE];
    #pragma unroll
    for (int d = 0; d < EE; ++d) {
        float ak = 0.f, av = 0.f;
        #pragma unroll
        for (int e = 0; e < EE; ++e) {
            ak = fmaf(xv[e], Wk[d*EE + e], ak);      // nn.Linear: x @ W^T
            av = fmaf(xv[e], Wv[d*EE + e], av);
        }
        kd[d] = ak; vd[d] = av;
    }

    #pragma unroll
    for (int h = 0; h < HH; ++h) {
        int gq = (b*HH + h)*SS + s;
        *reinterpret_cast<float4*>(qarr + (size_t)gq*4) =
            make_float4(qv[h*4+0], qv[h*4+1], qv[h*4+2], qv[h*4+3]);
        float4* kvp = reinterpret_cast<float4*>(kv + (size_t)gq*8);
        kvp[0] = make_float4(kd[h*4+0], kd[h*4+1], kd[h*4+2], kd[h*4+3]);
        kvp[1] = make_float4(vd[h*4+0], vd[h*4+1], vd[h*4+2], vd[h*4+3]);
    }
}

// ---------------------------------------------------------------------------
// Kernel B: flash attention, no running max. 8 queries/thread (amortizes the
// broadcast K/V reads 4x over the old 2/thread), packed-fp32 math
// (v_pk_fma_f32 via <2 x float>), native exp2. One block per (key-split, bh):
// grid (KS, B*H), 256 threads cover all 2048 queries.
// ---------------------------------------------------------------------------
__global__ __launch_bounds__(256) void attn_kernel(
    const float* __restrict__ qarr, const float* __restrict__ kv,
    float* __restrict__ accp, float* __restrict__ lp)
{
    __shared__ float4 skv[KLEN * 2];            // 64 keys x 32B = 2 KB

    int ks = blockIdx.x;                        // 0..KS-1
    int bh = blockIdx.y;                        // 0..15
    int gq0 = bh * SS + threadIdx.x * QPT;

    // Stage this block's K/V chunk: KLEN*2 = 128 float4.
    const float4* kvp =
        reinterpret_cast<const float4*>(kv + ((size_t)bh*SS + (size_t)ks*KLEN)*8);
    if (threadIdx.x < KLEN * 2) skv[threadIdx.x] = kvp[threadIdx.x];

    // Load 8 queries, pack component-wise into query-pairs.
    const float4* qv4 = reinterpret_cast<const float4*>(qarr + (size_t)gq0*4);
    v2f qx[4], qy[4], qz[4], qw[4];
    #pragma unroll
    for (int j = 0; j < 4; ++j) {
        float4 qa = qv4[2*j], qb = qv4[2*j+1];
        qx[j] = (v2f){qa.x, qb.x};
        qy[j] = (v2f){qa.y, qb.y};
        qz[j] = (v2f){qa.z, qb.z};
        qw[j] = (v2f){qa.w, qb.w};
    }

    __syncthreads();

    v2f accxy[QPT] = {}, acczw[QPT] = {};
    v2f lsum[4] = {};

    #pragma unroll 4
    for (int s = 0; s < KLEN; ++s) {
        float4 kk = skv[2*s];
        float4 vv = skv[2*s + 1];
        v2f kx = (v2f){kk.x, kk.x};
        v2f ky = (v2f){kk.y, kk.y};
        v2f kz = (v2f){kk.z, kk.z};
        v2f kw = (v2f){kk.w, kk.w};
        v2f vxy = (v2f){vv.x, vv.y};
        v2f vzw = (v2f){vv.z, vv.w};
        #pragma unroll
        for (int j = 0; j < 4; ++j) {
            v2f sc = __builtin_elementwise_fma(qx[j], kx,
                     __builtin_elementwise_fma(qy[j], ky,
                     __builtin_elementwise_fma(qz[j], kz, qw[j] * kw)));
            v2f p;
            p.x = __builtin_amdgcn_exp2f(sc.x);    // native v_exp_f32
            p.y = __builtin_amdgcn_exp2f(sc.y);
            lsum[j] += p;
            v2f p0 = __builtin_shufflevector(p, p, 0, 0);
            v2f p1 = __builtin_shufflevector(p, p, 1, 1);
            accxy[2*j]   = __builtin_elementwise_fma(p0, vxy, accxy[2*j]);
            acczw[2*j]   = __builtin_elementwise_fma(p0, vzw, acczw[2*j]);
            accxy[2*j+1] = __builtin_elementwise_fma(p1, vxy, accxy[2*j+1]);
            acczw[2*j+1] = __builtin_elementwise_fma(p1, vzw, acczw[2*j+1]);
        }
    }

    float4* ap = reinterpret_cast<float4*>(accp + ((size_t)ks*NQ + gq0)*4);
    #pragma unroll
    for (int i = 0; i < QPT; ++i)
        ap[i] = make_float4(accxy[i].x, accxy[i].y, acczw[i].x, acczw[i].y);
    #pragma unroll
    for (int j = 0; j < 4; ++j)
        *reinterpret_cast<v2f*>(lp + (size_t)ks*NQ + gq0 + 2*j) = lsum[j];
}

// ---------------------------------------------------------------------------
// Kernel C: combine key-split partials, normalize, apply Wc. One thread per
// token (all H heads so the cross-head Wc mix is local).
// ---------------------------------------------------------------------------
__global__ __launch_bounds__(256) void out_kernel(
    const float* __restrict__ accp, const float* __restrict__ lp,
    const float* __restrict__ Wc, float* __restrict__ out)
{
    int t = blockIdx.x * 256 + threadIdx.x;   // token 0..8191
    int b = t >> 11;
    int s = t & (SS - 1);

    float attn[EE];
    #pragma unroll
    for (int h = 0; h < HH; ++h) {
        int gq = (b*HH + h)*SS + s;
        float ax = 0.f, ay = 0.f, az = 0.f, aw = 0.f, l = 0.f;
        #pragma unroll
        for (int ks = 0; ks < KS; ++ks) {
            float4 a = *reinterpret_cast<const float4*>(accp + ((size_t)ks*NQ + gq)*4);
            ax += a.x; ay += a.y; az += a.z; aw += a.w;
            l += lp[(size_t)ks*NQ + gq];
        }
        float inv = 1.0f / l;
        attn[h*4+0] = ax*inv; attn[h*4+1] = ay*inv;
        attn[h*4+2] = az*inv; attn[h*4+3] = aw*inv;
    }

    float4* orow = reinterpret_cast<float4*>(out + (size_t)t * EE);
    #pragma unroll
    for (int e4 = 0; e4 < 4; ++e4) {
        float o[4];
        #pragma unroll
        for (int i = 0; i < 4; ++i) {
            int e = e4*4 + i;
            float acc = 0.f;
            #pragma unroll
            for (int j = 0; j < EE; ++j)
                acc = fmaf(attn[j], Wc[e*EE + j], acc);   // out = attn @ Wc^T
            o[i] = acc;
        }
        orow[e4] = make_float4(o[0], o[1], o[2], o[3]);
    }
}

// ---------------------------------------------------------------------------
extern "C" void kernel_launch(void* const* d_in, const int* in_sizes, int n_in,
                              void* d_out, int out_size, void* d_ws, size_t ws_size,
                              hipStream_t stream)
{
    const float* x     = (const float*)d_in[0];
    const float* theta = (const float*)d_in[1];
    const float* Wk    = (const float*)d_in[2];
    const float* Wv    = (const float*)d_in[3];
    const float* Wc    = (const float*)d_in[4];
    float* out = (float*)d_out;

    // Workspace carve (floats): qarr 512KB | kv 1MB | accp 16MB | lp 4MB
    float* ws   = (float*)d_ws;
    float* qarr = ws;                       // NQ*4
    float* kvb  = qarr + (size_t)NQ*4;      // NQ*8
    float* accp = kvb  + (size_t)NQ*8;      // KS*NQ*4
    float* lp   = accp + (size_t)KS*NQ*4;   // KS*NQ

    proj_kernel<<<dim3((BB*SS)/256), 256, 0, stream>>>(x, theta, Wk, Wv, qarr, kvb);
    attn_kernel<<<dim3(KS, BB*HH), 256, 0, stream>>>(qarr, kvb, accp, lp);
    out_kernel<<<dim3((BB*SS)/256), 256, 0, stream>>>(accp, lp, Wc, out);
}

// Round 5
// 92.484 us; speedup vs baseline: 1.1410x; 1.1410x over previous
//
#include <hip/hip_runtime.h>
#include <math.h>

// Problem constants (match reference)
#define BB 4
#define SS 2048
#define EE 16
#define HH 4
#define DK 4
#define KS 16                 // key splits: grid (16,16)=256 blocks x 8 waves
#define NQ (BB*HH*SS)         // 32768 total query rows
#define KLEN (SS/KS)          // 128 keys per split
#define QPT 4                 // queries per thread (512 threads cover S=2048)

// q pre-scaled by (1/sqrt(DK)) * log2(e): attn loop is pure exp2 domain.
// No-running-max softmax is safe: |log2 score| <= ~15 worst case -> exp2 sums
// stay far below fp32 overflow; equals reference softmax in exact arithmetic.
#define QSCALE 0.7213475204444817f   // 0.5 * log2(e)

// ---------------------------------------------------------------------------
// Kernel 1: fused proj + flash attention (no running max).
// Block (ks, bh): stages x[b, ks*KLEN .. +KLEN) (8 KB), computes K/V for its
// head in-block (once), q on the fly, then the exp2 inner loop over the
// staged chunk with broadcast LDS reads. Writes per-(ks,query) partial
// acc[4] and l. Scalar fp32 throughout (v2f packing regressed in R4).
// ---------------------------------------------------------------------------
__global__ __launch_bounds__(512) void attn_fused(
    const float* __restrict__ x, const float* __restrict__ theta,
    const float* __restrict__ Wk, const float* __restrict__ Wv,
    float* __restrict__ accp, float* __restrict__ lp)
{
    __shared__ float  sx[KLEN * EE];     // 128 tokens x 16 dims = 8 KB
    __shared__ float4 skv[KLEN * 2];     // {k4,v4} per key = 4 KB

    int tid = threadIdx.x;
    int ks = blockIdx.x;                 // 0..KS-1
    int bh = blockIdx.y;                 // 0..15
    int b = bh >> 2;
    int h = bh & 3;

    // --- stage x chunk: 512 float4 = 2048 floats, one per thread, coalesced
    const float4* xsrc =
        reinterpret_cast<const float4*>(x + ((size_t)b*SS + (size_t)ks*KLEN) * EE);
    reinterpret_cast<float4*>(sx)[tid] = xsrc[tid];

    // --- q for this thread's 4 queries (strided so stores coalesce):
    // x[b, s, h*4 .. h*4+3] is an aligned float4.
    float th0 = theta[h*4+0], th1 = theta[h*4+1];
    float th2 = theta[h*4+2], th3 = theta[h*4+3];   // uniform -> SGPR
    float4 qv[QPT];
    #pragma unroll
    for (int j = 0; j < QPT; ++j) {
        int s = tid + j*512;
        float4 xq = *reinterpret_cast<const float4*>(
            x + ((size_t)b*SS + s) * EE + h*4);
        qv[j].x = __cosf(xq.x + th0) * QSCALE;
        qv[j].y = __cosf(xq.y + th1) * QSCALE;
        qv[j].z = __cosf(xq.z + th2) * QSCALE;
        qv[j].w = __cosf(xq.w + th3) * QSCALE;
    }

    __syncthreads();

    // --- K/V for this head: threads 0..KLEN-1, one key each.
    if (tid < KLEN) {
        const float4* xr = reinterpret_cast<const float4*>(sx + tid * EE);
        float4 x0 = xr[0], x1 = xr[1], x2 = xr[2], x3 = xr[3];
        float xv[EE] = {x0.x,x0.y,x0.z,x0.w, x1.x,x1.y,x1.z,x1.w,
                        x2.x,x2.y,x2.z,x2.w, x3.x,x3.y,x3.z,x3.w};
        float kd[DK], vd[DK];
        #pragma unroll
        for (int d = 0; d < DK; ++d) {
            float ak = 0.f, av = 0.f;
            #pragma unroll
            for (int e = 0; e < EE; ++e) {
                ak = fmaf(xv[e], Wk[(h*4+d)*EE + e], ak);   // x @ W^T
                av = fmaf(xv[e], Wv[(h*4+d)*EE + e], av);
            }
            kd[d] = ak; vd[d] = av;
        }
        skv[2*tid]   = make_float4(kd[0], kd[1], kd[2], kd[3]);
        skv[2*tid+1] = make_float4(vd[0], vd[1], vd[2], vd[3]);
    }

    __syncthreads();

    // --- inner loop: broadcast LDS reads (conflict-free), scalar fp32.
    float4 acc[QPT] = {};
    float  lsum[QPT] = {};
    #pragma unroll 8
    for (int s = 0; s < KLEN; ++s) {
        float4 kk = skv[2*s];
        float4 vv = skv[2*s + 1];
        #pragma unroll
        for (int j = 0; j < QPT; ++j) {
            float sc = fmaf(qv[j].x, kk.x, fmaf(qv[j].y, kk.y,
                       fmaf(qv[j].z, kk.z, qv[j].w * kk.w)));
            float p = __builtin_amdgcn_exp2f(sc);    // native v_exp_f32
            lsum[j] += p;
            acc[j].x = fmaf(p, vv.x, acc[j].x);
            acc[j].y = fmaf(p, vv.y, acc[j].y);
            acc[j].z = fmaf(p, vv.z, acc[j].z);
            acc[j].w = fmaf(p, vv.w, acc[j].w);
        }
    }

    // --- store partials (lane-consecutive addresses -> dense coalescing)
    #pragma unroll
    for (int j = 0; j < QPT; ++j) {
        int gq = bh*SS + tid + j*512;
        *reinterpret_cast<float4*>(accp + ((size_t)ks*NQ + gq)*4) = acc[j];
        lp[(size_t)ks*NQ + gq] = lsum[j];
    }
}

// ---------------------------------------------------------------------------
// Kernel 2: combine key-split partials, normalize, apply Wc. One thread per
// token; 64-thread blocks x 128 so the VMEM latency spreads over 128 CUs.
// ---------------------------------------------------------------------------
__global__ __launch_bounds__(64) void out_kernel(
    const float* __restrict__ accp, const float* __restrict__ lp,
    const float* __restrict__ Wc, float* __restrict__ out)
{
    int t = blockIdx.x * 64 + threadIdx.x;    // token 0..8191
    int b = t >> 11;
    int s = t & (SS - 1);

    float attn[EE];
    #pragma unroll
    for (int h = 0; h < HH; ++h) {
        int gq = (b*HH + h)*SS + s;
        float ax = 0.f, ay = 0.f, az = 0.f, aw = 0.f, l = 0.f;
        #pragma unroll
        for (int ks = 0; ks < KS; ++ks) {
            float4 a = *reinterpret_cast<const float4*>(accp + ((size_t)ks*NQ + gq)*4);
            ax += a.x; ay += a.y; az += a.z; aw += a.w;
            l += lp[(size_t)ks*NQ + gq];
        }
        float inv = 1.0f / l;
        attn[h*4+0] = ax*inv; attn[h*4+1] = ay*inv;
        attn[h*4+2] = az*inv; attn[h*4+3] = aw*inv;
    }

    float4* orow = reinterpret_cast<float4*>(out + (size_t)t * EE);
    #pragma unroll
    for (int e4 = 0; e4 < 4; ++e4) {
        float o[4];
        #pragma unroll
        for (int i = 0; i < 4; ++i) {
            int e = e4*4 + i;
            float acc = 0.f;
            #pragma unroll
            for (int j = 0; j < EE; ++j)
                acc = fmaf(attn[j], Wc[e*EE + j], acc);   // out = attn @ Wc^T
            o[i] = acc;
        }
        orow[e4] = make_float4(o[0], o[1], o[2], o[3]);
    }
}

// ---------------------------------------------------------------------------
extern "C" void kernel_launch(void* const* d_in, const int* in_sizes, int n_in,
                              void* d_out, int out_size, void* d_ws, size_t ws_size,
                              hipStream_t stream)
{
    const float* x     = (const float*)d_in[0];
    const float* theta = (const float*)d_in[1];
    const float* Wk    = (const float*)d_in[2];
    const float* Wv    = (const float*)d_in[3];
    const float* Wc    = (const float*)d_in[4];
    float* out = (float*)d_out;

    // Workspace carve (floats): accp 8MB | lp 2MB
    float* ws   = (float*)d_ws;
    float* accp = ws;                       // KS*NQ*4
    float* lp   = accp + (size_t)KS*NQ*4;   // KS*NQ

    attn_fused<<<dim3(KS, BB*HH), 512, 0, stream>>>(x, theta, Wk, Wv, accp, lp);
    out_kernel<<<dim3((BB*SS)/64), 64, 0, stream>>>(accp, lp, Wc, out);
}

// Round 6
// 84.507 us; speedup vs baseline: 1.2487x; 1.0944x over previous
//
#include <hip/hip_runtime.h>
#include <math.h>

// Problem constants (match reference)
#define BB 4
#define SS 2048
#define EE 16
#define HH 4
#define DK 4
#define KS 8                  // key splits
#define NQ (BB*HH*SS)         // 32768 total query rows
#define KLEN (SS/KS)          // 256 keys per split
#define QPT 2                 // queries per thread (512 thr x 2 = 1024 q/block)

// q pre-scaled by (1/sqrt(DK)) * log2(e): attn loop is pure exp2 domain.
// No-running-max softmax is safe: |log2 score| <= ~15 worst case -> exp2 sums
// stay far below fp32 overflow; equals reference softmax in exact arithmetic.
#define QSCALE 0.7213475204444817f   // 0.5 * log2(e)

typedef float v2f __attribute__((ext_vector_type(2)));

// ---------------------------------------------------------------------------
// Kernel 1: fused proj + flash attention (no running max), packed across KEYS.
// Block (qchunk, ks, bh): threads 0..KLEN-1 compute K/V for this key chunk
// from global x (16 KB, L1/L2-shared by the 16 bh-blocks on the same chunk)
// into SoA LDS arrays; every thread computes q for its 2 queries on the fly.
// Inner loop: 4 keys/iter via broadcast float4 LDS reads (wave-uniform index
// -> conflict-free), v_pk_fma_f32 math on key-pairs, scalar native exp2.
// Writes per-(ks, query) partial acc[4] + l.
// ---------------------------------------------------------------------------
__global__ __launch_bounds__(512) void attn_fused(
    const float* __restrict__ x, const float* __restrict__ theta,
    const float* __restrict__ Wk, const float* __restrict__ Wv,
    float* __restrict__ accp, float* __restrict__ lp)
{
    __shared__ float skx[KLEN], sky[KLEN], skz[KLEN], skw[KLEN];
    __shared__ float svx[KLEN], svy[KLEN], svz[KLEN], svw[KLEN];

    int tid = threadIdx.x;
    int qc = blockIdx.x;                 // 0..1  query chunk
    int ks = blockIdx.y;                 // 0..KS-1
    int bh = blockIdx.z;                 // 0..15
    int b = bh >> 2;
    int h = bh & 3;

    // --- K/V for this chunk: threads 0..KLEN-1, one key each, from global x.
    if (tid < KLEN) {
        const float4* xr = reinterpret_cast<const float4*>(
            x + ((size_t)b*SS + (size_t)ks*KLEN + tid) * EE);
        float4 x0 = xr[0], x1 = xr[1], x2 = xr[2], x3 = xr[3];
        float xv[EE] = {x0.x,x0.y,x0.z,x0.w, x1.x,x1.y,x1.z,x1.w,
                        x2.x,x2.y,x2.z,x2.w, x3.x,x3.y,x3.z,x3.w};
        float kd[DK], vd[DK];
        #pragma unroll
        for (int d = 0; d < DK; ++d) {
            float ak = 0.f, av = 0.f;
            #pragma unroll
            for (int e = 0; e < EE; ++e) {
                ak = fmaf(xv[e], Wk[(h*4+d)*EE + e], ak);   // x @ W^T
                av = fmaf(xv[e], Wv[(h*4+d)*EE + e], av);
            }
            kd[d] = ak; vd[d] = av;
        }
        skx[tid] = kd[0]; sky[tid] = kd[1]; skz[tid] = kd[2]; skw[tid] = kd[3];
        svx[tid] = vd[0]; svy[tid] = vd[1]; svz[tid] = vd[2]; svw[tid] = vd[3];
    }

    // --- q for this thread's 2 queries (broadcast-duplicated into v2f).
    float th0 = theta[h*4+0], th1 = theta[h*4+1];
    float th2 = theta[h*4+2], th3 = theta[h*4+3];   // uniform -> SGPR
    int s0 = qc*1024 + tid;          // second query: s0 + 512
    float4 xq0 = *reinterpret_cast<const float4*>(x + ((size_t)b*SS + s0) * EE + h*4);
    float4 xq1 = *reinterpret_cast<const float4*>(x + ((size_t)b*SS + s0 + 512) * EE + h*4);
    float q0x = __cosf(xq0.x + th0) * QSCALE, q0y = __cosf(xq0.y + th1) * QSCALE;
    float q0z = __cosf(xq0.z + th2) * QSCALE, q0w = __cosf(xq0.w + th3) * QSCALE;
    float q1x = __cosf(xq1.x + th0) * QSCALE, q1y = __cosf(xq1.y + th1) * QSCALE;
    float q1z = __cosf(xq1.z + th2) * QSCALE, q1w = __cosf(xq1.w + th3) * QSCALE;
    v2f Q0x = {q0x,q0x}, Q0y = {q0y,q0y}, Q0z = {q0z,q0z}, Q0w = {q0w,q0w};
    v2f Q1x = {q1x,q1x}, Q1y = {q1y,q1y}, Q1z = {q1z,q1z}, Q1w = {q1w,q1w};

    __syncthreads();

    // --- inner loop: 4 keys per iter, packed key-pair math.
    v2f a0x = {}, a0y = {}, a0z = {}, a0w = {};
    v2f a1x = {}, a1y = {}, a1z = {}, a1w = {};
    v2f l0 = {}, l1 = {};
    const float4* kx4 = reinterpret_cast<const float4*>(skx);
    const float4* ky4 = reinterpret_cast<const float4*>(sky);
    const float4* kz4 = reinterpret_cast<const float4*>(skz);
    const float4* kw4 = reinterpret_cast<const float4*>(skw);
    const float4* vx4 = reinterpret_cast<const float4*>(svx);
    const float4* vy4 = reinterpret_cast<const float4*>(svy);
    const float4* vz4 = reinterpret_cast<const float4*>(svz);
    const float4* vw4 = reinterpret_cast<const float4*>(svw);

    #pragma unroll 2
    for (int i = 0; i < KLEN/4; ++i) {
        float4 kx = kx4[i], ky = ky4[i], kz = kz4[i], kw = kw4[i];
        float4 vx = vx4[i], vy = vy4[i], vz = vz4[i], vw = vw4[i];
        v2f kx01 = {kx.x, kx.y}, kx23 = {kx.z, kx.w};
        v2f ky01 = {ky.x, ky.y}, ky23 = {ky.z, ky.w};
        v2f kz01 = {kz.x, kz.y}, kz23 = {kz.z, kz.w};
        v2f kw01 = {kw.x, kw.y}, kw23 = {kw.z, kw.w};
        v2f vx01 = {vx.x, vx.y}, vx23 = {vx.z, vx.w};
        v2f vy01 = {vy.x, vy.y}, vy23 = {vy.z, vy.w};
        v2f vz01 = {vz.x, vz.y}, vz23 = {vz.z, vz.w};
        v2f vw01 = {vw.x, vw.y}, vw23 = {vw.z, vw.w};

        // query 0, key pair 01
        v2f sc = __builtin_elementwise_fma(Q0x, kx01,
                 __builtin_elementwise_fma(Q0y, ky01,
                 __builtin_elementwise_fma(Q0z, kz01, Q0w * kw01)));
        v2f p; p.x = __builtin_amdgcn_exp2f(sc.x); p.y = __builtin_amdgcn_exp2f(sc.y);
        l0 += p;
        a0x = __builtin_elementwise_fma(p, vx01, a0x);
        a0y = __builtin_elementwise_fma(p, vy01, a0y);
        a0z = __builtin_elementwise_fma(p, vz01, a0z);
        a0w = __builtin_elementwise_fma(p, vw01, a0w);
        // query 0, key pair 23
        sc = __builtin_elementwise_fma(Q0x, kx23,
             __builtin_elementwise_fma(Q0y, ky23,
             __builtin_elementwise_fma(Q0z, kz23, Q0w * kw23)));
        p.x = __builtin_amdgcn_exp2f(sc.x); p.y = __builtin_amdgcn_exp2f(sc.y);
        l0 += p;
        a0x = __builtin_elementwise_fma(p, vx23, a0x);
        a0y = __builtin_elementwise_fma(p, vy23, a0y);
        a0z = __builtin_elementwise_fma(p, vz23, a0z);
        a0w = __builtin_elementwise_fma(p, vw23, a0w);
        // query 1, key pair 01
        sc = __builtin_elementwise_fma(Q1x, kx01,
             __builtin_elementwise_fma(Q1y, ky01,
             __builtin_elementwise_fma(Q1z, kz01, Q1w * kw01)));
        p.x = __builtin_amdgcn_exp2f(sc.x); p.y = __builtin_amdgcn_exp2f(sc.y);
        l1 += p;
        a1x = __builtin_elementwise_fma(p, vx01, a1x);
        a1y = __builtin_elementwise_fma(p, vy01, a1y);
        a1z = __builtin_elementwise_fma(p, vz01, a1z);
        a1w = __builtin_elementwise_fma(p, vw01, a1w);
        // query 1, key pair 23
        sc = __builtin_elementwise_fma(Q1x, kx23,
             __builtin_elementwise_fma(Q1y, ky23,
             __builtin_elementwise_fma(Q1z, kz23, Q1w * kw23)));
        p.x = __builtin_amdgcn_exp2f(sc.x); p.y = __builtin_amdgcn_exp2f(sc.y);
        l1 += p;
        a1x = __builtin_elementwise_fma(p, vx23, a1x);
        a1y = __builtin_elementwise_fma(p, vy23, a1y);
        a1z = __builtin_elementwise_fma(p, vz23, a1z);
        a1w = __builtin_elementwise_fma(p, vw23, a1w);
    }

    // --- epilogue: fold key-pair lanes, store partials (lane-consecutive).
    int gq0 = bh*SS + s0;
    *reinterpret_cast<float4*>(accp + ((size_t)ks*NQ + gq0)*4) =
        make_float4(a0x.x + a0x.y, a0y.x + a0y.y, a0z.x + a0z.y, a0w.x + a0w.y);
    lp[(size_t)ks*NQ + gq0] = l0.x + l0.y;
    *reinterpret_cast<float4*>(accp + ((size_t)ks*NQ + gq0 + 512)*4) =
        make_float4(a1x.x + a1x.y, a1y.x + a1y.y, a1z.x + a1z.y, a1w.x + a1w.y);
    lp[(size_t)ks*NQ + gq0 + 512] = l1.x + l1.y;
}

// ---------------------------------------------------------------------------
// Kernel 2: combine key-split partials, normalize, apply Wc. One thread per
// token; 64-thread blocks x 128 so VMEM latency spreads over many CUs.
// ---------------------------------------------------------------------------
__global__ __launch_bounds__(64) void out_kernel(
    const float* __restrict__ accp, const float* __restrict__ lp,
    const float* __restrict__ Wc, float* __restrict__ out)
{
    int t = blockIdx.x * 64 + threadIdx.x;    // token 0..8191
    int b = t >> 11;
    int s = t & (SS - 1);

    float attn[EE];
    #pragma unroll
    for (int h = 0; h < HH; ++h) {
        int gq = (b*HH + h)*SS + s;
        float ax = 0.f, ay = 0.f, az = 0.f, aw = 0.f, l = 0.f;
        #pragma unroll
        for (int ks = 0; ks < KS; ++ks) {
            float4 a = *reinterpret_cast<const float4*>(accp + ((size_t)ks*NQ + gq)*4);
            ax += a.x; ay += a.y; az += a.z; aw += a.w;
            l += lp[(size_t)ks*NQ + gq];
        }
        float inv = 1.0f / l;
        attn[h*4+0] = ax*inv; attn[h*4+1] = ay*inv;
        attn[h*4+2] = az*inv; attn[h*4+3] = aw*inv;
    }

    float4* orow = reinterpret_cast<float4*>(out + (size_t)t * EE);
    #pragma unroll
    for (int e4 = 0; e4 < 4; ++e4) {
        float o[4];
        #pragma unroll
        for (int i = 0; i < 4; ++i) {
            int e = e4*4 + i;
            float acc = 0.f;
            #pragma unroll
            for (int j = 0; j < EE; ++j)
                acc = fmaf(attn[j], Wc[e*EE + j], acc);   // out = attn @ Wc^T
            o[i] = acc;
        }
        orow[e4] = make_float4(o[0], o[1], o[2], o[3]);
    }
}

// ---------------------------------------------------------------------------
extern "C" void kernel_launch(void* const* d_in, const int* in_sizes, int n_in,
                              void* d_out, int out_size, void* d_ws, size_t ws_size,
                              hipStream_t stream)
{
    const float* x     = (const float*)d_in[0];
    const float* theta = (const float*)d_in[1];
    const float* Wk    = (const float*)d_in[2];
    const float* Wv    = (const float*)d_in[3];
    const float* Wc    = (const float*)d_in[4];
    float* out = (float*)d_out;

    // Workspace carve (floats): accp 4MB | lp 1MB
    float* ws   = (float*)d_ws;
    float* accp = ws;                       // KS*NQ*4
    float* lp   = accp + (size_t)KS*NQ*4;   // KS*NQ

    attn_fused<<<dim3(2, KS, BB*HH), 512, 0, stream>>>(x, theta, Wk, Wv, accp, lp);
    out_kernel<<<dim3((BB*SS)/64), 64, 0, stream>>>(accp, lp, Wc, out);
}